// Round 4
// baseline (90.163 us; speedup 1.0000x reference)
//
#include <hip/hip_runtime.h>
#include <math.h>

#define GNUM 16
#define CDIM 128
#define SLOT (GNUM*CDIM + 2*GNUM)   // 2080 floats per partial slot
#define NBMAX 1024
#define NRSL 8                       // row-slices for the K2 reduction

typedef float v2f __attribute__((ext_vector_type(2)));

// ---------------- Kernel 1: normalize + register-resident segment accumulate ----------------
// 256 threads = 4 waves. ONE ROW PER WAVE: lane l loads float2 = channels (2l, 2l+1),
// so the wave covers the full 128-channel row and the group id g = scores[r] is
// WAVE-UNIFORM -> readfirstlane + scalar switch dispatch: a single v_pk_add per row
// instead of a 16-way cndmask/fma chain. Batch-4 rows + one-batch-ahead prefetch
// keeps 4 row-loads (2KB) in flight per wave for latency hiding.
__global__ __launch_bounds__(256, 4)
void oc_accum(const float* __restrict__ feat, const int* __restrict__ scores,
              float* __restrict__ partial, int B)
{
    __shared__ float ws_sum[4][GNUM][CDIM];   // 32 KB, epilogue only
    __shared__ float ws_cnt[4][GNUM];
    __shared__ float ws_sq [4][GNUM];

    const int tid  = threadIdx.x;
    const int wave = tid >> 6;
    const int lane = tid & 63;

    v2f acc[GNUM];
    #pragma unroll
    for (int gg = 0; gg < GNUM; ++gg) acc[gg] = (v2f)0.f;
    float cnt = 0.f, sq = 0.f;

    const int gw = blockIdx.x*4 + wave;
    const int nw = gridDim.x*4;

    // contiguous chunk of rows per wave, in batches of 4
    const int nbat  = (B + 3) >> 2;
    const int bbase = nbat / nw;
    const int brem  = nbat % nw;
    const int b0    = gw*bbase + (gw < brem ? gw : brem);
    const int bcnt  = bbase + (gw < brem ? 1 : 0);
    const int rbeg  = b0 * 4;
    const int rend  = min(rbeg + bcnt*4, B);    // rows [rbeg, rend)

    const float2* fbase = reinterpret_cast<const float2*>(feat) + lane;

    // process one (valid) row: x = this lane's 2 channels, graw = scores[r] (same in all lanes)
    auto proc = [&](float2 x, int graw) {
        float ss = fmaf(x.x, x.x, x.y*x.y);
        ss += __shfl_xor(ss, 1);
        ss += __shfl_xor(ss, 2);
        ss += __shfl_xor(ss, 4);
        ss += __shfl_xor(ss, 8);
        ss += __shfl_xor(ss, 16);
        ss += __shfl_xor(ss, 32);
        const float inv = (ss > 1e-24f) ? rsqrtf(ss) : 1e12f;   // == 1/max(sqrt(ss),1e-12)
        const int g = __builtin_amdgcn_readfirstlane(graw);
        v2f xv; xv.x = x.x*inv; xv.y = x.y*inv;
        switch (g) {
            case  0: acc[ 0] += xv; break;
            case  1: acc[ 1] += xv; break;
            case  2: acc[ 2] += xv; break;
            case  3: acc[ 3] += xv; break;
            case  4: acc[ 4] += xv; break;
            case  5: acc[ 5] += xv; break;
            case  6: acc[ 6] += xv; break;
            case  7: acc[ 7] += xv; break;
            case  8: acc[ 8] += xv; break;
            case  9: acc[ 9] += xv; break;
            case 10: acc[10] += xv; break;
            case 11: acc[11] += xv; break;
            case 12: acc[12] += xv; break;
            case 13: acc[13] += xv; break;
            case 14: acc[14] += xv; break;
            case 15: acc[15] += xv; break;
            default: break;
        }
        if (lane == g) { cnt += 1.0f; sq = fmaf(ss, inv*inv, sq); }
    };

    // batch loader: rows r0..r0+3 (uniform guards), scores as one int4 when safe
    auto loadB = [&](int r0, float2& a, float2& b, float2& c, float2& d, int4& s) {
        const float2* p = fbase + (size_t)r0 * 64;
        a = p[0];
        b = (r0+1 < rend) ? p[64]  : make_float2(0.f, 0.f);
        c = (r0+2 < rend) ? p[128] : make_float2(0.f, 0.f);
        d = (r0+3 < rend) ? p[192] : make_float2(0.f, 0.f);
        if (r0 + 4 <= B) {
            s = *reinterpret_cast<const int4*>(scores + r0);
        } else {
            s.x = scores[r0];
            s.y = (r0+1 < B) ? scores[r0+1] : 0;
            s.z = (r0+2 < B) ? scores[r0+2] : 0;
            s.w = (r0+3 < B) ? scores[r0+3] : 0;
        }
    };

    if (rbeg < rend) {
        float2 a, b, c, d; int4 s;
        loadB(rbeg, a, b, c, d, s);
        for (int r0 = rbeg; r0 < rend; r0 += 4) {
            float2 na, nb_, nc, nd; int4 ns;
            na = nb_ = nc = nd = make_float2(0.f, 0.f);
            ns = make_int4(0, 0, 0, 0);
            const int r1 = r0 + 4;
            if (r1 < rend) loadB(r1, na, nb_, nc, nd, ns);   // prefetch next batch
            proc(a, s.x);
            if (r0+1 < rend) proc(b, s.y);
            if (r0+2 < rend) proc(c, s.z);
            if (r0+3 < rend) proc(d, s.w);
            a = na; b = nb_; c = nc; d = nd; s = ns;
        }
    }

    // per-wave LDS stores: lane l holds channels (2l, 2l+1) of every group
    #pragma unroll
    for (int gg = 0; gg < GNUM; ++gg)
        *reinterpret_cast<v2f*>(&ws_sum[wave][gg][lane*2]) = acc[gg];
    if (lane < GNUM) { ws_cnt[wave][lane] = cnt; ws_sq[wave][lane] = sq; }
    __syncthreads();

    // block-level reduce of the 4 wave copies, write partial slot
    float* out = partial + (size_t)blockIdx.x * SLOT;
    const float* f0 = &ws_sum[0][0][0];
    const float* f1 = &ws_sum[1][0][0];
    const float* f2 = &ws_sum[2][0][0];
    const float* f3 = &ws_sum[3][0][0];
    for (int e = tid; e < GNUM*CDIM; e += 256)
        out[e] = f0[e] + f1[e] + f2[e] + f3[e];
    if (tid < GNUM) {
        out[GNUM*CDIM + tid]        = ws_cnt[0][tid] + ws_cnt[1][tid] + ws_cnt[2][tid] + ws_cnt[3][tid];
        out[GNUM*CDIM + GNUM + tid] = ws_sq [0][tid] + ws_sq [1][tid] + ws_sq [2][tid] + ws_sq [3][tid];
    }
}

// ---------------- Kernel 2: parallel column reduction of partial slots ----------------
// grid (ceil(SLOT/64), NRSL): blockIdx.y picks a row-slice; output NRSL partial vectors.
__global__ __launch_bounds__(256)
void oc_reduce(const float* __restrict__ partial, float* __restrict__ fin8, int nb)
{
    __shared__ float sdata[256];
    const int e     = blockIdx.x*64 + (threadIdx.x & 63);
    const int blane = threadIdx.x >> 6;
    float acc = 0.f;
    if (e < SLOT)
        for (int b = blockIdx.y + blane*NRSL; b < nb; b += 4*NRSL)
            acc += partial[(size_t)b*SLOT + e];
    sdata[threadIdx.x] = acc;
    __syncthreads();
    if (threadIdx.x < 64 && e < SLOT)
        fin8[(size_t)blockIdx.y*SLOT + e] =
            sdata[threadIdx.x] + sdata[threadIdx.x + 64] +
            sdata[threadIdx.x + 128] + sdata[threadIdx.x + 192];
}

// ---------------- Kernel 3: sum slices + remap/compact + loss ----------------
__global__ __launch_bounds__(256)
void oc_loss(const float* __restrict__ fin8, float* __restrict__ out)
{
    __shared__ float FIN[SLOT];
    __shared__ float M[GNUM][CDIM];
    __shared__ float MS[GNUM];
    __shared__ float Cs[GNUM];
    __shared__ int   srcmap[GNUM];
    __shared__ int   Ush;
    __shared__ float red[4];

    const int tid = threadIdx.x;

    for (int e = tid; e < SLOT; e += 256) {
        float a = 0.f;
        #pragma unroll
        for (int r = 0; r < NRSL; ++r) a += fin8[(size_t)r*SLOT + e];
        FIN[e] = a;
    }
    __syncthreads();

    if (tid < GNUM) Cs[tid] = FIN[GNUM*CDIM + tid];
    __syncthreads();

    if (tid == 0) {
        int u = 0;
        for (int g = 0; g < GNUM; ++g)
            if (Cs[g] > 0.f) srcmap[u++] = g;
        Ush = u;
        for (int k = u; k < GNUM; ++k) srcmap[k] = -1;
    }
    __syncthreads();
    const int U = Ush;

    for (int e = tid; e < GNUM*CDIM; e += 256) {
        const int u = e >> 7, c = e & 127;
        const int g = srcmap[u];
        M[u][c] = (g >= 0) ? FIN[g*CDIM + c] / fmaxf(Cs[g], 1.f) : 0.f;
    }
    if (tid < GNUM) {
        const int g = srcmap[tid];
        MS[tid] = (g >= 0) ? FIN[GNUM*CDIM + GNUM + g] / fmaxf(Cs[g], 1.f) : 0.f;
    }
    __syncthreads();

    float acc = 0.f;
    for (int e = tid; e < (GNUM-2)*CDIM; e += 256) {
        const int i = e >> 7, c = e & 127;
        if (i + 2 < U) {
            const float m1 = M[i][c], m2 = M[i+1][c], m3 = M[i+2][c];
            acc += m2*(m1 + m3) - m1*m3;
        }
    }
    acc += __shfl_xor(acc, 1);
    acc += __shfl_xor(acc, 2);
    acc += __shfl_xor(acc, 4);
    acc += __shfl_xor(acc, 8);
    acc += __shfl_xor(acc, 16);
    acc += __shfl_xor(acc, 32);
    if ((tid & 63) == 0) red[tid >> 6] = acc;
    __syncthreads();

    if (tid == 0) {
        float tot = red[0] + red[1] + red[2] + red[3];
        for (int i = 0; i < GNUM-2; ++i)
            if (i + 2 < U) tot -= MS[i+1];
        out[0] = tot / (float)(U - 2);
    }
}

extern "C" void kernel_launch(void* const* d_in, const int* in_sizes, int n_in,
                              void* d_out, int out_size, void* d_ws, size_t ws_size,
                              hipStream_t stream) {
    const float* feat   = (const float*)d_in[0];
    const int*   scores = (const int*)d_in[1];
    float*       out    = (float*)d_out;

    const int B = in_sizes[1];               // number of rows

    // ws layout: [nb * SLOT] partial slots, then [NRSL * SLOT] slice vectors.
    long long cap = (long long)(ws_size / (SLOT * sizeof(float))) - NRSL;
    int nb = (int)(cap < 1 ? 1 : (cap > NBMAX ? NBMAX : cap));

    float* partial = (float*)d_ws;
    float* fin8    = partial + (size_t)nb * SLOT;

    hipLaunchKernelGGL(oc_accum,  dim3(nb), dim3(256), 0, stream, feat, scores, partial, B);
    hipLaunchKernelGGL(oc_reduce, dim3((SLOT + 63) / 64, NRSL), dim3(256), 0, stream, partial, fin8, nb);
    hipLaunchKernelGGL(oc_loss,   dim3(1), dim3(256), 0, stream, fin8, out);
}

// Round 5
// 74.632 us; speedup vs baseline: 1.2081x; 1.2081x over previous
//
#include <hip/hip_runtime.h>
#include <math.h>

#define GNUM 16
#define CDIM 128
#define SLOT (GNUM*CDIM + 2*GNUM)   // 2080 floats per partial slot
#define NBMAX 1024
#define NRSL 8                       // row-slices for the K2 reduction

typedef float v2f __attribute__((ext_vector_type(2)));

// ---------------- Kernel 1: normalize + register-resident segment accumulate ----------------
// 256 threads = 4 waves. Each wave owns a contiguous chunk of row-PAIRS.
// Per pair p: lane loads float4 at pair-base + lane*16B -> lanes 0-31 = row 2p,
// lanes 32-63 = row 2p+1 (16B/lane coalescing sweet spot).
// No LDS / no atomics / no branches in the hot loop. Depth-6 rotating register
// ring keeps ~6KB of loads in flight per wave (Little's law: latency hiding).
__global__ __launch_bounds__(256, 4)
void oc_accum(const float* __restrict__ feat, const int* __restrict__ scores,
              float* __restrict__ partial, int B, int npairs)
{
    __shared__ float ws_sum[4][GNUM][CDIM];   // 32 KB, epilogue only
    __shared__ float ws_cnt[4][GNUM];
    __shared__ float ws_sq [4][GNUM];

    const int tid  = threadIdx.x;
    const int wave = tid >> 6;
    const int lane = tid & 63;
    const int hl   = lane & 31;       // lane within half-wave (channels hl*4..hl*4+3)
    const int half = lane >> 5;       // which row of the pair

    v2f acc[GNUM][2];
    #pragma unroll
    for (int gg = 0; gg < GNUM; ++gg) { acc[gg][0] = (v2f)0.f; acc[gg][1] = (v2f)0.f; }
    float cnt = 0.f, sq = 0.f;

    const int gw = blockIdx.x*4 + wave;
    const int nw = gridDim.x*4;

    // contiguous balanced chunks
    const int base = npairs / nw;
    const int rem_ = npairs % nw;
    const int pbeg = gw * base + (gw < rem_ ? gw : rem_);
    const int pcnt = base + (gw < rem_ ? 1 : 0);

    auto process = [&](float4 x, int g) {
        float ss = x.x*x.x + x.y*x.y + x.z*x.z + x.w*x.w;
        ss += __shfl_xor(ss, 1);
        ss += __shfl_xor(ss, 2);
        ss += __shfl_xor(ss, 4);
        ss += __shfl_xor(ss, 8);
        ss += __shfl_xor(ss, 16);           // masks <32 never cross the half boundary
        const float inv = (ss > 1e-24f) ? rsqrtf(ss) : 1e12f;   // == 1/max(sqrt(ss),1e-12)
        const v2f xlo = {x.x, x.y};
        const v2f xhi = {x.z, x.w};
        #pragma unroll
        for (int gg = 0; gg < GNUM; ++gg) {
            const float w = (g == gg) ? inv : 0.0f;
            const v2f wv = {w, w};
            acc[gg][0] = xlo * wv + acc[gg][0];   // v_pk_fma_f32
            acc[gg][1] = xhi * wv + acc[gg][1];
        }
        if (g == hl) { cnt += 1.0f; sq = fmaf(ss, inv*inv, sq); }
    };

    const float4* src = reinterpret_cast<const float4*>(feat);

    if (pcnt > 0) {
        const int plast = pbeg + pcnt - 1;
        auto LD = [&](int p, float4& x, int& g) {
            const int pc = (p < plast) ? p : plast;    // clamp: branchless, always valid
            x = src[(size_t)pc*32 + lane];
            g = scores[2*pc + half];
        };

        float4 x0,x1,x2,x3,x4,x5; int g0,g1,g2,g3,g4,g5;
        LD(pbeg+0, x0,g0); LD(pbeg+1, x1,g1); LD(pbeg+2, x2,g2);
        LD(pbeg+3, x3,g3); LD(pbeg+4, x4,g4); LD(pbeg+5, x5,g5);

        int i = 0;
        for (; i + 6 <= pcnt; i += 6) {
            process(x0,g0); LD(pbeg+i+6,  x0,g0);
            process(x1,g1); LD(pbeg+i+7,  x1,g1);
            process(x2,g2); LD(pbeg+i+8,  x2,g2);
            process(x3,g3); LD(pbeg+i+9,  x3,g3);
            process(x4,g4); LD(pbeg+i+10, x4,g4);
            process(x5,g5); LD(pbeg+i+11, x5,g5);
        }
        const int rem = pcnt - i;          // 0..5
        if (rem > 0) process(x0,g0);
        if (rem > 1) process(x1,g1);
        if (rem > 2) process(x2,g2);
        if (rem > 3) process(x3,g3);
        if (rem > 4) process(x4,g4);
    }

    // odd B: the unpaired last row, handled once by wave 0 (half-1 lanes contribute nothing)
    if ((B & 1) && gw == 0) {
        float4 xo = make_float4(0.f,0.f,0.f,0.f);
        int go = -1;
        if (half == 0) {
            xo = src[(size_t)(B-1)*32 + hl];
            go = scores[B-1];
        }
        process(xo, go);
    }

    // combine the two halves of the wave in-register
    #pragma unroll
    for (int gg = 0; gg < GNUM; ++gg) {
        acc[gg][0].x += __shfl_xor(acc[gg][0].x, 32);
        acc[gg][0].y += __shfl_xor(acc[gg][0].y, 32);
        acc[gg][1].x += __shfl_xor(acc[gg][1].x, 32);
        acc[gg][1].y += __shfl_xor(acc[gg][1].y, 32);
    }
    cnt += __shfl_xor(cnt, 32);
    sq  += __shfl_xor(sq, 32);

    // direct (non-RMW) per-wave LDS stores
    if (half == 0) {
        #pragma unroll
        for (int gg = 0; gg < GNUM; ++gg) {
            *reinterpret_cast<v2f*>(&ws_sum[wave][gg][hl*4])     = acc[gg][0];
            *reinterpret_cast<v2f*>(&ws_sum[wave][gg][hl*4 + 2]) = acc[gg][1];
        }
        if (hl < GNUM) { ws_cnt[wave][hl] = cnt; ws_sq[wave][hl] = sq; }
    }
    __syncthreads();

    // block-level reduce of the 4 wave copies, write partial slot
    float* out = partial + (size_t)blockIdx.x * SLOT;
    const float* f0 = &ws_sum[0][0][0];
    const float* f1 = &ws_sum[1][0][0];
    const float* f2 = &ws_sum[2][0][0];
    const float* f3 = &ws_sum[3][0][0];
    for (int e = tid; e < GNUM*CDIM; e += 256)
        out[e] = f0[e] + f1[e] + f2[e] + f3[e];
    if (tid < GNUM) {
        out[GNUM*CDIM + tid]        = ws_cnt[0][tid] + ws_cnt[1][tid] + ws_cnt[2][tid] + ws_cnt[3][tid];
        out[GNUM*CDIM + GNUM + tid] = ws_sq [0][tid] + ws_sq [1][tid] + ws_sq [2][tid] + ws_sq [3][tid];
    }
}

// ---------------- Kernel 2: parallel column reduction of partial slots ----------------
// grid (ceil(SLOT/64), NRSL): blockIdx.y picks a row-slice; output NRSL partial vectors.
__global__ __launch_bounds__(256)
void oc_reduce(const float* __restrict__ partial, float* __restrict__ fin8, int nb)
{
    __shared__ float sdata[256];
    const int e     = blockIdx.x*64 + (threadIdx.x & 63);
    const int blane = threadIdx.x >> 6;
    float acc = 0.f;
    if (e < SLOT)
        for (int b = blockIdx.y + blane*NRSL; b < nb; b += 4*NRSL)
            acc += partial[(size_t)b*SLOT + e];
    sdata[threadIdx.x] = acc;
    __syncthreads();
    if (threadIdx.x < 64 && e < SLOT)
        fin8[(size_t)blockIdx.y*SLOT + e] =
            sdata[threadIdx.x] + sdata[threadIdx.x + 64] +
            sdata[threadIdx.x + 128] + sdata[threadIdx.x + 192];
}

// ---------------- Kernel 3: sum slices + remap/compact + loss ----------------
__global__ __launch_bounds__(256)
void oc_loss(const float* __restrict__ fin8, float* __restrict__ out)
{
    __shared__ float FIN[SLOT];
    __shared__ float M[GNUM][CDIM];
    __shared__ float MS[GNUM];
    __shared__ float Cs[GNUM];
    __shared__ int   srcmap[GNUM];
    __shared__ int   Ush;
    __shared__ float red[4];

    const int tid = threadIdx.x;

    for (int e = tid; e < SLOT; e += 256) {
        float a = 0.f;
        #pragma unroll
        for (int r = 0; r < NRSL; ++r) a += fin8[(size_t)r*SLOT + e];
        FIN[e] = a;
    }
    __syncthreads();

    if (tid < GNUM) Cs[tid] = FIN[GNUM*CDIM + tid];
    __syncthreads();

    if (tid == 0) {
        int u = 0;
        for (int g = 0; g < GNUM; ++g)
            if (Cs[g] > 0.f) srcmap[u++] = g;
        Ush = u;
        for (int k = u; k < GNUM; ++k) srcmap[k] = -1;
    }
    __syncthreads();
    const int U = Ush;

    for (int e = tid; e < GNUM*CDIM; e += 256) {
        const int u = e >> 7, c = e & 127;
        const int g = srcmap[u];
        M[u][c] = (g >= 0) ? FIN[g*CDIM + c] / fmaxf(Cs[g], 1.f) : 0.f;
    }
    if (tid < GNUM) {
        const int g = srcmap[tid];
        MS[tid] = (g >= 0) ? FIN[GNUM*CDIM + GNUM + g] / fmaxf(Cs[g], 1.f) : 0.f;
    }
    __syncthreads();

    float acc = 0.f;
    for (int e = tid; e < (GNUM-2)*CDIM; e += 256) {
        const int i = e >> 7, c = e & 127;
        if (i + 2 < U) {
            const float m1 = M[i][c], m2 = M[i+1][c], m3 = M[i+2][c];
            acc += m2*(m1 + m3) - m1*m3;
        }
    }
    acc += __shfl_xor(acc, 1);
    acc += __shfl_xor(acc, 2);
    acc += __shfl_xor(acc, 4);
    acc += __shfl_xor(acc, 8);
    acc += __shfl_xor(acc, 16);
    acc += __shfl_xor(acc, 32);
    if ((tid & 63) == 0) red[tid >> 6] = acc;
    __syncthreads();

    if (tid == 0) {
        float tot = red[0] + red[1] + red[2] + red[3];
        for (int i = 0; i < GNUM-2; ++i)
            if (i + 2 < U) tot -= MS[i+1];
        out[0] = tot / (float)(U - 2);
    }
}

extern "C" void kernel_launch(void* const* d_in, const int* in_sizes, int n_in,
                              void* d_out, int out_size, void* d_ws, size_t ws_size,
                              hipStream_t stream) {
    const float* feat   = (const float*)d_in[0];
    const int*   scores = (const int*)d_in[1];
    float*       out    = (float*)d_out;

    const int B      = in_sizes[1];          // number of rows
    const int npairs = B / 2;                // full pairs (odd row handled in-kernel)

    // ws layout: [nb * SLOT] partial slots, then [NRSL * SLOT] slice vectors.
    long long cap = (long long)(ws_size / (SLOT * sizeof(float))) - NRSL;
    int nb = (int)(cap < 1 ? 1 : (cap > NBMAX ? NBMAX : cap));

    float* partial = (float*)d_ws;
    float* fin8    = partial + (size_t)nb * SLOT;

    hipLaunchKernelGGL(oc_accum,  dim3(nb), dim3(256), 0, stream, feat, scores, partial, B, npairs);
    hipLaunchKernelGGL(oc_reduce, dim3((SLOT + 63) / 64, NRSL), dim3(256), 0, stream, partial, fin8, nb);
    hipLaunchKernelGGL(oc_loss,   dim3(1), dim3(256), 0, stream, fin8, out);
}